// Round 1
// 146.144 us; speedup vs baseline: 1.0331x; 1.0331x over previous
//
#include <hip/hip_runtime.h>

// QuantizedActorMLP: x(1M,17) -> quant -> L1(17->64)+quantact -> L2(64->64)+quantact -> L3(64->6)
// Integer-exact bf16 MFMA (ints |n|<=127 exact in bf16, sums < 2^24 exact in fp32 acc).
// R10: R9 + (a) scalarized wave id via readfirstlane -> all tile addressing/guards in
//      SALU/SGPR (loads become v_laneoff + s[base] + imm, no per-iter VALU addr math),
//      (b) branch guards replaced by scalar min-clamps (dup processing of last tile is
//      benign), (c) depth-2 register prefetch (xa/xb, 2-unrolled loop) so x loads get
//      ~2 full iterations of compute to land (VGPR-neutral vs old xv/xn + copy),
//      (d) q>=2 zero lanes initialized once, never touched in the loop,
//      (e) float4 preamble staging for W2/W3.
//      MFMA structure, fragments, quant math, epilogues identical to R9 (absmax 0.0068).

typedef __attribute__((ext_vector_type(8))) short short8;    // MFMA A/B frag (8 bf16)
typedef __attribute__((ext_vector_type(4))) float floatx4;   // MFMA C/D frag
typedef __attribute__((ext_vector_type(4))) unsigned int uint4v;
typedef unsigned int uint;

__device__ __forceinline__ uint f32bits(float v) { union { float f; uint u; } c; c.f = v; return c.u; }
__device__ __forceinline__ short bf16i(float v) { return (short)(f32bits(v) >> 16); }
// pack two integer-valued f32 -> two bf16 in one uint (low = z0): one v_perm_b32
__device__ __forceinline__ uint pack2(float z0, float z1) {
  return __builtin_amdgcn_perm(f32bits(z1), f32bits(z0), 0x07060302u);
}
// round-to-nearest-even integer clamped to [-127,127]: v_med3 + v_rndne
__device__ __forceinline__ float qclamp(float v) {
  return __builtin_rintf(__builtin_amdgcn_fmed3f(v, -127.f, 127.f));
}
__device__ __forceinline__ int imin(int a, int b) { return a < b ? a : b; }

__global__ void __launch_bounds__(256) qmlp_fused(
    const float* __restrict__ x,
    const float* __restrict__ W1, const float* __restrict__ b1,
    const float* __restrict__ W2, const float* __restrict__ b2,
    const float* __restrict__ W3, const float* __restrict__ b3,
    float* __restrict__ out, int B)
{
  constexpr float QMAXF = 127.0f;
  constexpr float SCALE = 1.33f;
  const float step  = SCALE / QMAXF;
  const float istep = QMAXF / SCALE;

  __shared__ __align__(16) float wraw1[64 * 17];   // W1 raw, pitch 17
  __shared__ float wraw2[64 * 65];                 // W2 raw, pitch 65 (pad kills gather conflicts)
  __shared__ float wraw3[6 * 65];                  // W3 raw, pitch 65
  __shared__ float redv[12];                       // per-wave (m1,m2,m3)

  const int tid  = threadIdx.x;
  const int lane = tid & 63;
  const int bi   = lane & 15;
  const int q    = lane >> 4;

  // ---- coalesced staging of raw weights into LDS, max-abs fused into the load ----
  float m1 = 0.f, m2 = 0.f, m3 = 0.f;
  for (int i = tid; i < 272; i += 256) {                       // W1: 1088 floats = 272 float4
    float4 v = ((const float4*)W1)[i];
    ((float4*)wraw1)[i] = v;
    m1 = fmaxf(m1, fmaxf(fmaxf(fabsf(v.x), fabsf(v.y)), fmaxf(fabsf(v.z), fabsf(v.w))));
  }
  for (int i = tid; i < 1024; i += 256) {                      // W2: 4096 floats = 1024 float4
    float4 v = ((const float4*)W2)[i];
    int r = i >> 4, c0 = (i & 15) * 4;                         // rows of 64: no float4 crosses a row
    float* dst = &wraw2[r * 65 + c0];
    dst[0] = v.x; dst[1] = v.y; dst[2] = v.z; dst[3] = v.w;
    m2 = fmaxf(m2, fmaxf(fmaxf(fabsf(v.x), fabsf(v.y)), fmaxf(fabsf(v.z), fabsf(v.w))));
  }
  for (int i = tid; i < 96; i += 256) {                        // W3: 384 floats = 96 float4
    float4 v = ((const float4*)W3)[i];
    int r = i >> 4, c0 = (i & 15) * 4;
    float* dst = &wraw3[r * 65 + c0];
    dst[0] = v.x; dst[1] = v.y; dst[2] = v.z; dst[3] = v.w;
    m3 = fmaxf(m3, fmaxf(fmaxf(fabsf(v.x), fabsf(v.y)), fmaxf(fabsf(v.z), fabsf(v.w))));
  }
  #pragma unroll
  for (int off = 32; off > 0; off >>= 1) {
    m1 = fmaxf(m1, __shfl_down(m1, off));
    m2 = fmaxf(m2, __shfl_down(m2, off));
    m3 = fmaxf(m3, __shfl_down(m3, off));
  }
  if (lane == 0) {
    int w4 = tid >> 6;
    redv[w4 * 3 + 0] = m1; redv[w4 * 3 + 1] = m2; redv[w4 * 3 + 2] = m3;
  }
  __syncthreads();                 // the ONLY barrier: publishes redv + wraw1/2/3
  float s1 = 0.f, s2 = 0.f, s3 = 0.f;
  #pragma unroll
  for (int i = 0; i < 4; ++i) {
    s1 = fmaxf(s1, redv[i * 3 + 0]);
    s2 = fmaxf(s2, redv[i * 3 + 1]);
    s3 = fmaxf(s3, redv[i * 3 + 2]);
  }
  s1 /= QMAXF; s2 /= QMAXF; s3 /= QMAXF;
  const float rs1 = 1.0f / s1, rs2 = 1.0f / s2, rs3 = 1.0f / s3;

  // ---- scalarized work decomposition (everything tile-related lives in SGPRs) ----
  const int ntiles = B >> 4;                                   // 16-row tiles (65536)
  const int nw     = (int)(gridDim.x << 2);                    // waves total (4096)
  const int wid    = __builtin_amdgcn_readfirstlane((int)(blockIdx.x << 2) + (tid >> 6));
  const int nIter  = (ntiles + nw - 1) / nw;                   // 16
  const int lastt  = ntiles - 1;

  const int loff  = bi * 17 + 8 * q;                           // dword offset within tile (q<2)
  const int loff2 = bi * 17 + 16;                              // q==2 single element

  // ---- weight fragments (integer-valued bf16) from LDS (reciprocal-mul quant) ----
  short8 w1f[4];
  #pragma unroll
  for (int t = 0; t < 4; ++t) {
    #pragma unroll
    for (int j = 0; j < 8; ++j) {
      int k = 8 * q + j;
      float wv = (k < 17) ? wraw1[(16 * t + bi) * 17 + k] : 0.f;
      float wi = fminf(fmaxf(rintf(wv * rs1), -QMAXF), QMAXF);
      w1f[t][j] = bf16i(wi);
    }
  }
  // K-permutation: eta = 32s + 16(j>>2) + 4q + (j&3) so layer-L C/D regs feed layer-(L+1) B-frags.
  short8 w2f[4][2];
  #pragma unroll
  for (int t = 0; t < 4; ++t) {
    #pragma unroll
    for (int s = 0; s < 2; ++s) {
      #pragma unroll
      for (int j = 0; j < 8; ++j) {
        int eta = 32 * s + 16 * (j >> 2) + 4 * q + (j & 3);
        float wv = wraw2[(16 * t + bi) * 65 + eta];
        float wi = fminf(fmaxf(rintf(wv * rs2), -QMAXF), QMAXF);
        w2f[t][s][j] = bf16i(wi);
      }
    }
  }
  short8 w3f[2];
  #pragma unroll
  for (int s = 0; s < 2; ++s) {
    #pragma unroll
    for (int j = 0; j < 8; ++j) {
      int eta = 32 * s + 16 * (j >> 2) + 4 * q + (j & 3);
      float wv = (bi < 6) ? wraw3[bi * 65 + eta] : 0.f;
      float wi = fminf(fmaxf(rintf(wv * rs3), -QMAXF), QMAXF);
      w3f[s][j] = bf16i(wi);
    }
  }

  // ---- per-slot biases in integer units (few lines each, L2-hot) ----
  const float g1 = (s1 * step) * istep;
  const float g2 = (s2 * step) * istep;
  const float sc3 = s3 * step;
  float b1s[4][4], b2s[4][4], b3s[4];
  #pragma unroll
  for (int t = 0; t < 4; ++t) {
    #pragma unroll
    for (int r = 0; r < 4; ++r) {
      b1s[t][r] = b1[16 * t + 4 * q + r] * istep;
      b2s[t][r] = b2[16 * t + 4 * q + r] * istep;
    }
  }
  #pragma unroll
  for (int r = 0; r < 4; ++r) {
    int n = 4 * q + r;
    b3s[r] = (n < 6) ? b3[n] : 0.f;
  }

  const floatx4 zero4 = {0.f, 0.f, 0.f, 0.f};

  // ---- depth-2 register double-buffer of per-lane direct x loads ----
  float xa[8], xb[8];
  #pragma unroll
  for (int j = 0; j < 8; ++j) { xa[j] = 0.f; xb[j] = 0.f; }    // q>=2 pad lanes stay 0 forever

  auto issue = [&](int t, float (&xr)[8]) {
    const float* tp = x + (size_t)t * 272;                     // SGPR base (t is scalar)
    if (q < 2) {
      #pragma unroll
      for (int j = 0; j < 8; ++j) xr[j] = tp[loff + j];        // 8x global_load_dword, imm offsets
    } else if (q == 2) {
      xr[0] = tp[loff2];
    }
  };

  auto quantpack = [&](const float (&xr)[8]) -> short8 {
    uint4v ap;
    #pragma unroll
    for (int jp = 0; jp < 4; ++jp)
      ap[jp] = pack2(qclamp(xr[2 * jp] * istep), qclamp(xr[2 * jp + 1] * istep));
    return __builtin_bit_cast(short8, ap);
  };

  auto mlp = [&](short8 af, int gt) {
    // L1
    floatx4 c1[4];
    #pragma unroll
    for (int t = 0; t < 4; ++t)
      c1[t] = __builtin_amdgcn_mfma_f32_16x16x32_bf16(w1f[t], af, zero4, 0, 0, 0);

    uint4v h1u[2];
    #pragma unroll
    for (int t = 0; t < 4; ++t) {
      float z0 = qclamp(fmaf(c1[t][0], g1, b1s[t][0]));
      float z1 = qclamp(fmaf(c1[t][1], g1, b1s[t][1]));
      float z2 = qclamp(fmaf(c1[t][2], g1, b1s[t][2]));
      float z3 = qclamp(fmaf(c1[t][3], g1, b1s[t][3]));
      h1u[t >> 1][(t & 1) * 2 + 0] = pack2(z0, z1);
      h1u[t >> 1][(t & 1) * 2 + 1] = pack2(z2, z3);
    }
    short8 h1a = __builtin_bit_cast(short8, h1u[0]);
    short8 h1b = __builtin_bit_cast(short8, h1u[1]);

    // L2 (K=64)
    floatx4 c2[4];
    #pragma unroll
    for (int t = 0; t < 4; ++t) {
      c2[t] = __builtin_amdgcn_mfma_f32_16x16x32_bf16(w2f[t][0], h1a, zero4, 0, 0, 0);
      c2[t] = __builtin_amdgcn_mfma_f32_16x16x32_bf16(w2f[t][1], h1b, c2[t], 0, 0, 0);
    }

    uint4v h2u[2];
    #pragma unroll
    for (int t = 0; t < 4; ++t) {
      float z0 = qclamp(fmaf(c2[t][0], g2, b2s[t][0]));
      float z1 = qclamp(fmaf(c2[t][1], g2, b2s[t][1]));
      float z2 = qclamp(fmaf(c2[t][2], g2, b2s[t][2]));
      float z3 = qclamp(fmaf(c2[t][3], g2, b2s[t][3]));
      h2u[t >> 1][(t & 1) * 2 + 0] = pack2(z0, z1);
      h2u[t >> 1][(t & 1) * 2 + 1] = pack2(z2, z3);
    }
    short8 h2a = __builtin_bit_cast(short8, h2u[0]);
    short8 h2b = __builtin_bit_cast(short8, h2u[1]);

    // L3
    floatx4 c3;
    c3 = __builtin_amdgcn_mfma_f32_16x16x32_bf16(w3f[0], h2a, zero4, 0, 0, 0);
    c3 = __builtin_amdgcn_mfma_f32_16x16x32_bf16(w3f[1], h2b, c3, 0, 0, 0);

    float o0 = fmaf(c3[0], sc3, b3s[0]);
    float o1 = fmaf(c3[1], sc3, b3s[1]);
    float o2 = fmaf(c3[2], sc3, b3s[2]);
    float o3 = fmaf(c3[3], sc3, b3s[3]);
    float* orow = out + (size_t)gt * 96 + bi * 6;              // SGPR base + small lane offset
    if (q == 0) {
      *(float2*)(orow)     = make_float2(o0, o1);
      *(float2*)(orow + 2) = make_float2(o2, o3);
    } else if (q == 1) {
      *(float2*)(orow + 4) = make_float2(o0, o1);
    }
  };

  // ---- prologue: fill both buffers ----
  issue(imin(wid, lastt), xa);
  issue(imin(wid + nw, lastt), xb);

  // ---- main loop: 2-unrolled, no LDS, no barriers, loads get ~2 iterations to land ----
  int it = 0;
  for (; it + 1 < nIter; it += 2) {
    {
      int gt = imin(wid + it * nw, lastt);
      short8 af = quantpack(xa);                               // waits on xa's loads only
      issue(imin(wid + (it + 2) * nw, lastt), xa);             // refill immediately (WAR ok)
      mlp(af, gt);
    }
    {
      int gt = imin(wid + (it + 1) * nw, lastt);
      short8 af = quantpack(xb);
      issue(imin(wid + (it + 3) * nw, lastt), xb);
      mlp(af, gt);
    }
  }
  if (it < nIter) {                                            // odd tail (dead for B=1M)
    int gt = imin(wid + it * nw, lastt);
    mlp(quantpack(xa), gt);
  }
}

extern "C" void kernel_launch(void* const* d_in, const int* in_sizes, int n_in,
                              void* d_out, int out_size, void* d_ws, size_t ws_size,
                              hipStream_t stream) {
  const float* x  = (const float*)d_in[0];
  const float* W1 = (const float*)d_in[1];
  const float* b1 = (const float*)d_in[2];
  const float* W2 = (const float*)d_in[3];
  const float* b2 = (const float*)d_in[4];
  const float* W3 = (const float*)d_in[5];
  const float* b3 = (const float*)d_in[6];
  float* out = (float*)d_out;
  const int B = in_sizes[0] / 17;          // 1048576

  dim3 grid(1024), block(256);             // 4096 waves x 16 iterations, 4 blocks/CU
  qmlp_fused<<<grid, block, 0, stream>>>(x, W1, b1, W2, b2, W3, b3, out, B);
}

// Round 2
// 141.457 us; speedup vs baseline: 1.0673x; 1.0331x over previous
//
#include <hip/hip_runtime.h>

// QuantizedActorMLP: x(1M,17) -> quant -> L1(17->64)+quantact -> L2(64->64)+quantact -> L3(64->6)
// Integer-exact bf16 MFMA (ints |n|<=127 exact in bf16, sums < 2^24 exact in fp32 acc).
// R11: coalesce both memory legs (theory: per-CU vector-mem front end was saturated by
//      scatter: 272 lane-dwords @68B stride + scattered float2 stores ~ 300+ TA-cycles/wave-iter).
//  - x tile (1088B) staged via 2x global_load_lds dwordx4 into a wave-private LDS double
//    buffer (reusing the weight-staging LDS after fragment extraction; +1 barrier).
//    Tail instr uses clamped duplicate lane addresses -> zero OOB even on the last tile.
//  - fragment gather = 8x ds_read_b32 at stride-17-dword (max 2-way bank alias = free).
//  - counted waits: issue-after-consume, s_waitcnt vmcnt(1) at loop top (vmcnt(0) iter 0).
//  - output funneled through a 96-dword per-wave LDS buffer -> ONE global_store_dwordx4
//    by lanes 0..23 (6 contiguous lines vs ~32 scattered segments).
//  MFMA structure, fragments, quant math identical to R10 (verified, absmax 0.0068).

typedef __attribute__((ext_vector_type(8))) short short8;    // MFMA A/B frag (8 bf16)
typedef __attribute__((ext_vector_type(4))) float floatx4;   // MFMA C/D frag
typedef __attribute__((ext_vector_type(4))) unsigned int uint4v;
typedef unsigned int uint;

__device__ __forceinline__ uint f32bits(float v) { union { float f; uint u; } c; c.f = v; return c.u; }
__device__ __forceinline__ short bf16i(float v) { return (short)(f32bits(v) >> 16); }
// pack two integer-valued f32 -> two bf16 in one uint (low = z0): one v_perm_b32
__device__ __forceinline__ uint pack2(float z0, float z1) {
  return __builtin_amdgcn_perm(f32bits(z1), f32bits(z0), 0x07060302u);
}
// round-to-nearest-even integer clamped to [-127,127]: v_med3 + v_rndne
__device__ __forceinline__ float qclamp(float v) {
  return __builtin_rintf(__builtin_amdgcn_fmed3f(v, -127.f, 127.f));
}
__device__ __forceinline__ int imin(int a, int b) { return a < b ? a : b; }

// async global->LDS, 16B per lane: LDS dest = (uniform) l + lane*16, global src per-lane.
__device__ __forceinline__ void gld16(const float* g, float* l) {
  __builtin_amdgcn_global_load_lds((__attribute__((address_space(1))) void*)(g),
                                   (__attribute__((address_space(3))) void*)(l),
                                   16, 0, 0);
}

__global__ void __launch_bounds__(256) qmlp_fused(
    const float* __restrict__ x,
    const float* __restrict__ W1, const float* __restrict__ b1,
    const float* __restrict__ W2, const float* __restrict__ b2,
    const float* __restrict__ W3, const float* __restrict__ b3,
    float* __restrict__ out, int B)
{
  constexpr float QMAXF = 127.0f;
  constexpr float SCALE = 1.33f;
  const float step  = SCALE / QMAXF;
  const float istep = QMAXF / SCALE;

  // One shared pool, two lifetimes:
  //  preamble: wraw1[0..1088) wraw2[1088..5248) wraw3[5248..5638) redv[5638..5650)
  //  main loop: x double-buffers [w*1024 + d*512, +512) for wave w, buf d  (4096 dw)
  //             out funnel       [4096 + w*104, +96)                      (<=4512 dw)
  __shared__ __align__(16) float smem[5650];
  float* wraw1 = smem;            // W1 raw, pitch 17
  float* wraw2 = smem + 1088;     // W2 raw, pitch 65 (pad kills gather conflicts)
  float* wraw3 = smem + 5248;     // W3 raw, pitch 65
  float* redv  = smem + 5638;     // per-wave (m1,m2,m3)

  const int tid  = threadIdx.x;
  const int lane = tid & 63;
  const int bi   = lane & 15;
  const int q    = lane >> 4;
  const int w    = tid >> 6;

  // ---- coalesced staging of raw weights into LDS, max-abs fused into the load ----
  float m1 = 0.f, m2 = 0.f, m3 = 0.f;
  for (int i = tid; i < 272; i += 256) {                       // W1: 1088 floats = 272 float4
    float4 v = ((const float4*)W1)[i];
    ((float4*)wraw1)[i] = v;
    m1 = fmaxf(m1, fmaxf(fmaxf(fabsf(v.x), fabsf(v.y)), fmaxf(fabsf(v.z), fabsf(v.w))));
  }
  for (int i = tid; i < 1024; i += 256) {                      // W2: 4096 floats = 1024 float4
    float4 v = ((const float4*)W2)[i];
    int r = i >> 4, c0 = (i & 15) * 4;                         // no float4 crosses a 64-row
    float* dst = &wraw2[r * 65 + c0];
    dst[0] = v.x; dst[1] = v.y; dst[2] = v.z; dst[3] = v.w;
    m2 = fmaxf(m2, fmaxf(fmaxf(fabsf(v.x), fabsf(v.y)), fmaxf(fabsf(v.z), fabsf(v.w))));
  }
  for (int i = tid; i < 96; i += 256) {                        // W3: 384 floats = 96 float4
    float4 v = ((const float4*)W3)[i];
    int r = i >> 4, c0 = (i & 15) * 4;
    float* dst = &wraw3[r * 65 + c0];
    dst[0] = v.x; dst[1] = v.y; dst[2] = v.z; dst[3] = v.w;
    m3 = fmaxf(m3, fmaxf(fmaxf(fabsf(v.x), fabsf(v.y)), fmaxf(fabsf(v.z), fabsf(v.w))));
  }
  #pragma unroll
  for (int off = 32; off > 0; off >>= 1) {
    m1 = fmaxf(m1, __shfl_down(m1, off));
    m2 = fmaxf(m2, __shfl_down(m2, off));
    m3 = fmaxf(m3, __shfl_down(m3, off));
  }
  if (lane == 0) {
    redv[w * 3 + 0] = m1; redv[w * 3 + 1] = m2; redv[w * 3 + 2] = m3;
  }
  __syncthreads();                 // barrier 1: publishes redv + wraw1/2/3
  float s1 = 0.f, s2 = 0.f, s3 = 0.f;
  #pragma unroll
  for (int i = 0; i < 4; ++i) {
    s1 = fmaxf(s1, redv[i * 3 + 0]);
    s2 = fmaxf(s2, redv[i * 3 + 1]);
    s3 = fmaxf(s3, redv[i * 3 + 2]);
  }
  s1 /= QMAXF; s2 /= QMAXF; s3 /= QMAXF;
  const float rs1 = 1.0f / s1, rs2 = 1.0f / s2, rs3 = 1.0f / s3;

  // ---- weight fragments (integer-valued bf16) from LDS (reciprocal-mul quant) ----
  short8 w1f[4];
  #pragma unroll
  for (int t = 0; t < 4; ++t) {
    #pragma unroll
    for (int j = 0; j < 8; ++j) {
      int k = 8 * q + j;
      float wv = (k < 17) ? wraw1[(16 * t + bi) * 17 + k] : 0.f;
      float wi = fminf(fmaxf(rintf(wv * rs1), -QMAXF), QMAXF);
      w1f[t][j] = bf16i(wi);
    }
  }
  // K-permutation: eta = 32s + 16(j>>2) + 4q + (j&3) so layer-L C/D regs feed layer-(L+1) B-frags.
  short8 w2f[4][2];
  #pragma unroll
  for (int t = 0; t < 4; ++t) {
    #pragma unroll
    for (int s = 0; s < 2; ++s) {
      #pragma unroll
      for (int j = 0; j < 8; ++j) {
        int eta = 32 * s + 16 * (j >> 2) + 4 * q + (j & 3);
        float wv = wraw2[(16 * t + bi) * 65 + eta];
        float wi = fminf(fmaxf(rintf(wv * rs2), -QMAXF), QMAXF);
        w2f[t][s][j] = bf16i(wi);
      }
    }
  }
  short8 w3f[2];
  #pragma unroll
  for (int s = 0; s < 2; ++s) {
    #pragma unroll
    for (int j = 0; j < 8; ++j) {
      int eta = 32 * s + 16 * (j >> 2) + 4 * q + (j & 3);
      float wv = (bi < 6) ? wraw3[bi * 65 + eta] : 0.f;
      float wi = fminf(fmaxf(rintf(wv * rs3), -QMAXF), QMAXF);
      w3f[s][j] = bf16i(wi);
    }
  }

  __syncthreads();                 // barrier 2: weight LDS dead -> safe to reuse for x staging

  // ---- per-slot biases in integer units (few lines each, L2-hot) ----
  const float g1 = (s1 * step) * istep;
  const float g2 = (s2 * step) * istep;
  const float sc3 = s3 * step;
  float b1s[4][4], b2s[4][4], b3s[4];
  #pragma unroll
  for (int t = 0; t < 4; ++t) {
    #pragma unroll
    for (int r = 0; r < 4; ++r) {
      b1s[t][r] = b1[16 * t + 4 * q + r] * istep;
      b2s[t][r] = b2[16 * t + 4 * q + r] * istep;
    }
  }
  #pragma unroll
  for (int r = 0; r < 4; ++r) {
    int n = 4 * q + r;
    b3s[r] = (n < 6) ? b3[n] : 0.f;
  }

  // ---- scalarized work decomposition ----
  const int ntiles = B >> 4;                                   // 65536
  const int nw     = (int)(gridDim.x << 2);                    // 4096 waves
  const int wid    = __builtin_amdgcn_readfirstlane((int)(blockIdx.x << 2) + w);
  const int nIter  = (ntiles + nw - 1) / nw;                   // 16
  const int lastt  = ntiles - 1;

  float* xb0  = smem + w * 1024;                               // two 512-dword buffers
  float* obuf = smem + 4096 + w * 104;                         // 96-dword out funnel

  const int lane4 = lane * 4;
  const int tailo = 256 + 4 * imin(lane, 3);                   // clamped dup for lanes>=4
  const int fbase = bi * 17 + 8 * q;                           // frag base (q<2)
  const int fb2   = bi * 17 + 16;                              // q==2 single element

  auto stage = [&](int t, float* buf) {
    const float* tp = x + (size_t)t * 272;
    gld16(tp + lane4, buf);                                    // dwords 0..255, coalesced
    gld16(tp + tailo, buf + 256);                              // dwords 256..271 (+junk pad)
  };

  const floatx4 zero4 = {0.f, 0.f, 0.f, 0.f};

  // ---- prologue: fill buffer 0 ----
  stage(wid, xb0);

  #pragma unroll 1
  for (int it = 0; it < nIter; ++it) {
    const int gt = imin(wid + it * nw, lastt);
    float* cur = xb0 + (it & 1) * 512;

    // retire this buffer's 2 loads; allow last iter's 1 store to stay outstanding
    if (it == 0) { asm volatile("s_waitcnt vmcnt(0)" ::: "memory"); }
    else         { asm volatile("s_waitcnt vmcnt(1)" ::: "memory"); }

    // fragment gather from LDS (stride-17-dword: max 2-way bank alias = free)
    float xr[8];
    if (q < 2) {
      #pragma unroll
      for (int j = 0; j < 8; ++j) xr[j] = cur[fbase + j];
    } else if (q == 2) {
      xr[0] = cur[fb2];
      #pragma unroll
      for (int j = 1; j < 8; ++j) xr[j] = 0.f;
    } else {
      #pragma unroll
      for (int j = 0; j < 8; ++j) xr[j] = 0.f;
    }

    // issue next tile AFTER consuming (keeps the conservative wait from draining it)
    if (it + 1 < nIter) stage(wid + (it + 1) * nw, xb0 + ((it + 1) & 1) * 512);

    // input quant -> B-frag: lane holds Xq[row=bi][k=8q+j]
    uint4v ap;
    #pragma unroll
    for (int jp = 0; jp < 4; ++jp)
      ap[jp] = pack2(qclamp(xr[2 * jp] * istep), qclamp(xr[2 * jp + 1] * istep));
    short8 af = __builtin_bit_cast(short8, ap);

    // L1
    floatx4 c1[4];
    #pragma unroll
    for (int t = 0; t < 4; ++t)
      c1[t] = __builtin_amdgcn_mfma_f32_16x16x32_bf16(w1f[t], af, zero4, 0, 0, 0);

    uint4v h1u[2];
    #pragma unroll
    for (int t = 0; t < 4; ++t) {
      float z0 = qclamp(fmaf(c1[t][0], g1, b1s[t][0]));
      float z1 = qclamp(fmaf(c1[t][1], g1, b1s[t][1]));
      float z2 = qclamp(fmaf(c1[t][2], g1, b1s[t][2]));
      float z3 = qclamp(fmaf(c1[t][3], g1, b1s[t][3]));
      h1u[t >> 1][(t & 1) * 2 + 0] = pack2(z0, z1);
      h1u[t >> 1][(t & 1) * 2 + 1] = pack2(z2, z3);
    }
    short8 h1a = __builtin_bit_cast(short8, h1u[0]);
    short8 h1b = __builtin_bit_cast(short8, h1u[1]);

    // L2 (K=64)
    floatx4 c2[4];
    #pragma unroll
    for (int t = 0; t < 4; ++t) {
      c2[t] = __builtin_amdgcn_mfma_f32_16x16x32_bf16(w2f[t][0], h1a, zero4, 0, 0, 0);
      c2[t] = __builtin_amdgcn_mfma_f32_16x16x32_bf16(w2f[t][1], h1b, c2[t], 0, 0, 0);
    }

    uint4v h2u[2];
    #pragma unroll
    for (int t = 0; t < 4; ++t) {
      float z0 = qclamp(fmaf(c2[t][0], g2, b2s[t][0]));
      float z1 = qclamp(fmaf(c2[t][1], g2, b2s[t][1]));
      float z2 = qclamp(fmaf(c2[t][2], g2, b2s[t][2]));
      float z3 = qclamp(fmaf(c2[t][3], g2, b2s[t][3]));
      h2u[t >> 1][(t & 1) * 2 + 0] = pack2(z0, z1);
      h2u[t >> 1][(t & 1) * 2 + 1] = pack2(z2, z3);
    }
    short8 h2a = __builtin_bit_cast(short8, h2u[0]);
    short8 h2b = __builtin_bit_cast(short8, h2u[1]);

    // L3
    floatx4 c3;
    c3 = __builtin_amdgcn_mfma_f32_16x16x32_bf16(w3f[0], h2a, zero4, 0, 0, 0);
    c3 = __builtin_amdgcn_mfma_f32_16x16x32_bf16(w3f[1], h2b, c3, 0, 0, 0);

    float o0 = fmaf(c3[0], sc3, b3s[0]);
    float o1 = fmaf(c3[1], sc3, b3s[1]);
    float o2 = fmaf(c3[2], sc3, b3s[2]);
    float o3 = fmaf(c3[3], sc3, b3s[3]);

    // funnel the 16x6 tile through LDS -> one coalesced dwordx4 store (lanes 0..23)
    if (q == 0) {
      *(float2*)(obuf + bi * 6)     = make_float2(o0, o1);     // ds_write_b64 (24B stride: no conflict)
      *(float2*)(obuf + bi * 6 + 2) = make_float2(o2, o3);
    } else if (q == 1) {
      *(float2*)(obuf + bi * 6 + 4) = make_float2(o0, o1);
    }
    asm volatile("" ::: "memory");                             // pin write->read order (same wave, LDS in-order)
    if (lane < 24) {
      float4 v = *(const float4*)(obuf + lane4);               // ds_read_b128
      *(float4*)(out + (size_t)gt * 96 + lane4) = v;           // ONE global_store_dwordx4 (6 lines)
    }
  }
}

extern "C" void kernel_launch(void* const* d_in, const int* in_sizes, int n_in,
                              void* d_out, int out_size, void* d_ws, size_t ws_size,
                              hipStream_t stream) {
  const float* x  = (const float*)d_in[0];
  const float* W1 = (const float*)d_in[1];
  const float* b1 = (const float*)d_in[2];
  const float* W2 = (const float*)d_in[3];
  const float* b2 = (const float*)d_in[4];
  const float* W3 = (const float*)d_in[5];
  const float* b3 = (const float*)d_in[6];
  float* out = (float*)d_out;
  const int B = in_sizes[0] / 17;          // 1048576

  dim3 grid(1024), block(256);             // 4096 waves x 16 iterations, 4 blocks/CU
  qmlp_fused<<<grid, block, 0, stream>>>(x, W1, b1, W2, b2, W3, b3, out, B);
}

// Round 4
// 138.784 us; speedup vs baseline: 1.0879x; 1.0193x over previous
//
#include <hip/hip_runtime.h>

// QuantizedActorMLP: x(1M,17) -> quant -> L1(17->64)+quantact -> L2(64->64)+quantact -> L3(64->6)
// Integer-exact bf16 MFMA (ints |n|<=127 exact in bf16, sums < 2^24 exact in fp32 acc).
// R13: R12 (4-tile super-iterations) with the staging-overflow bug fixed.
//  R12 BUG: tail gld16 with clamped SOURCE still advances the LDS dest by lane*16 for all
//  64 lanes -> lanes 16..63 wrote 192 dwords past the buffer into the next wave's staged
//  input (global_load_lds dest is ALWAYS base+lane*size). Fix: tail uses size=4
//  global_load_lds -> one dword/lane, 64 dwords exactly, no overflow, no source clamp.
//  Structure: each wave stages 4 consecutive tiles (4352B contiguous) with 4x dwordx4 +
//  1x dword global_load_lds (double-buffered), ONE s_waitcnt vmcnt(2)/super-iteration;
//  outputs staged IN-PLACE over consumed input LDS; 2 contiguous global_store_dwordx4.
//  Per-tile MFMA core, quant math, fragments verbatim from R11 (verified, absmax 0.0068).

typedef __attribute__((ext_vector_type(8))) short short8;    // MFMA A/B frag (8 bf16)
typedef __attribute__((ext_vector_type(4))) float floatx4;   // MFMA C/D frag
typedef __attribute__((ext_vector_type(4))) unsigned int uint4v;
typedef unsigned int uint;

__device__ __forceinline__ uint f32bits(float v) { union { float f; uint u; } c; c.f = v; return c.u; }
__device__ __forceinline__ short bf16i(float v) { return (short)(f32bits(v) >> 16); }
// pack two integer-valued f32 -> two bf16 in one uint (low = z0): one v_perm_b32
__device__ __forceinline__ uint pack2(float z0, float z1) {
  return __builtin_amdgcn_perm(f32bits(z1), f32bits(z0), 0x07060302u);
}
// round-to-nearest-even integer clamped to [-127,127]: v_med3 + v_rndne
__device__ __forceinline__ float qclamp(float v) {
  return __builtin_rintf(__builtin_amdgcn_fmed3f(v, -127.f, 127.f));
}
__device__ __forceinline__ int imin(int a, int b) { return a < b ? a : b; }

// async global->LDS: LDS dest = (uniform) l + lane*size, global src per-lane.
__device__ __forceinline__ void gld16(const float* g, float* l) {
  __builtin_amdgcn_global_load_lds((__attribute__((address_space(1))) void*)(g),
                                   (__attribute__((address_space(3))) void*)(l),
                                   16, 0, 0);
}
__device__ __forceinline__ void gld4(const float* g, float* l) {
  __builtin_amdgcn_global_load_lds((__attribute__((address_space(1))) void*)(g),
                                   (__attribute__((address_space(3))) void*)(l),
                                   4, 0, 0);
}

__global__ void __launch_bounds__(256) qmlp_fused(
    const float* __restrict__ x,
    const float* __restrict__ W1, const float* __restrict__ b1,
    const float* __restrict__ W2, const float* __restrict__ b2,
    const float* __restrict__ W3, const float* __restrict__ b3,
    float* __restrict__ out, int B)
{
  constexpr float QMAXF = 127.0f;
  constexpr float SCALE = 1.33f;
  const float step  = SCALE / QMAXF;
  const float istep = QMAXF / SCALE;

  // One shared pool, two lifetimes:
  //  preamble: wraw1[0..1088) wraw2[1088..5248) wraw3[5248..5638) redv[5638..5650)
  //  main loop: per-wave x double-buffer [w*2176 + d*1088, +1088)  (8704 dw total)
  __shared__ __align__(16) float smem[8704];
  float* wraw1 = smem;            // W1 raw, pitch 17
  float* wraw2 = smem + 1088;     // W2 raw, pitch 65 (pad kills gather conflicts)
  float* wraw3 = smem + 5248;     // W3 raw, pitch 65
  float* redv  = smem + 5638;     // per-wave (m1,m2,m3)

  const int tid  = threadIdx.x;
  const int lane = tid & 63;
  const int bi   = lane & 15;
  const int q    = lane >> 4;
  const int w    = tid >> 6;

  // ---- coalesced staging of raw weights into LDS, max-abs fused into the load ----
  float m1 = 0.f, m2 = 0.f, m3 = 0.f;
  for (int i = tid; i < 272; i += 256) {                       // W1: 1088 floats = 272 float4
    float4 v = ((const float4*)W1)[i];
    ((float4*)wraw1)[i] = v;
    m1 = fmaxf(m1, fmaxf(fmaxf(fabsf(v.x), fabsf(v.y)), fmaxf(fabsf(v.z), fabsf(v.w))));
  }
  for (int i = tid; i < 1024; i += 256) {                      // W2: 4096 floats = 1024 float4
    float4 v = ((const float4*)W2)[i];
    int r = i >> 4, c0 = (i & 15) * 4;                         // no float4 crosses a 64-row
    float* dst = &wraw2[r * 65 + c0];
    dst[0] = v.x; dst[1] = v.y; dst[2] = v.z; dst[3] = v.w;
    m2 = fmaxf(m2, fmaxf(fmaxf(fabsf(v.x), fabsf(v.y)), fmaxf(fabsf(v.z), fabsf(v.w))));
  }
  for (int i = tid; i < 96; i += 256) {                        // W3: 384 floats = 96 float4
    float4 v = ((const float4*)W3)[i];
    int r = i >> 4, c0 = (i & 15) * 4;
    float* dst = &wraw3[r * 65 + c0];
    dst[0] = v.x; dst[1] = v.y; dst[2] = v.z; dst[3] = v.w;
    m3 = fmaxf(m3, fmaxf(fmaxf(fabsf(v.x), fabsf(v.y)), fmaxf(fabsf(v.z), fabsf(v.w))));
  }
  #pragma unroll
  for (int off = 32; off > 0; off >>= 1) {
    m1 = fmaxf(m1, __shfl_down(m1, off));
    m2 = fmaxf(m2, __shfl_down(m2, off));
    m3 = fmaxf(m3, __shfl_down(m3, off));
  }
  if (lane == 0) {
    redv[w * 3 + 0] = m1; redv[w * 3 + 1] = m2; redv[w * 3 + 2] = m3;
  }
  __syncthreads();                 // barrier 1: publishes redv + wraw1/2/3
  float s1 = 0.f, s2 = 0.f, s3 = 0.f;
  #pragma unroll
  for (int i = 0; i < 4; ++i) {
    s1 = fmaxf(s1, redv[i * 3 + 0]);
    s2 = fmaxf(s2, redv[i * 3 + 1]);
    s3 = fmaxf(s3, redv[i * 3 + 2]);
  }
  s1 /= QMAXF; s2 /= QMAXF; s3 /= QMAXF;
  const float rs1 = 1.0f / s1, rs2 = 1.0f / s2, rs3 = 1.0f / s3;

  // ---- weight fragments (integer-valued bf16) from LDS (reciprocal-mul quant) ----
  short8 w1f[4];
  #pragma unroll
  for (int t = 0; t < 4; ++t) {
    #pragma unroll
    for (int j = 0; j < 8; ++j) {
      int k = 8 * q + j;
      float wv = (k < 17) ? wraw1[(16 * t + bi) * 17 + k] : 0.f;
      float wi = fminf(fmaxf(rintf(wv * rs1), -QMAXF), QMAXF);
      w1f[t][j] = bf16i(wi);
    }
  }
  // K-permutation: eta = 32s + 16(j>>2) + 4q + (j&3) so layer-L C/D regs feed layer-(L+1) B-frags.
  short8 w2f[4][2];
  #pragma unroll
  for (int t = 0; t < 4; ++t) {
    #pragma unroll
    for (int s = 0; s < 2; ++s) {
      #pragma unroll
      for (int j = 0; j < 8; ++j) {
        int eta = 32 * s + 16 * (j >> 2) + 4 * q + (j & 3);
        float wv = wraw2[(16 * t + bi) * 65 + eta];
        float wi = fminf(fmaxf(rintf(wv * rs2), -QMAXF), QMAXF);
        w2f[t][s][j] = bf16i(wi);
      }
    }
  }
  short8 w3f[2];
  #pragma unroll
  for (int s = 0; s < 2; ++s) {
    #pragma unroll
    for (int j = 0; j < 8; ++j) {
      int eta = 32 * s + 16 * (j >> 2) + 4 * q + (j & 3);
      float wv = (bi < 6) ? wraw3[bi * 65 + eta] : 0.f;
      float wi = fminf(fmaxf(rintf(wv * rs3), -QMAXF), QMAXF);
      w3f[s][j] = bf16i(wi);
    }
  }

  __syncthreads();                 // barrier 2: weight LDS dead -> safe to reuse for x staging

  // ---- per-slot biases in integer units (few lines each, L2-hot) ----
  const float g1 = (s1 * step) * istep;
  const float g2 = (s2 * step) * istep;
  const float sc3 = s3 * step;
  float b1s[4][4], b2s[4][4], b3s[4];
  #pragma unroll
  for (int t = 0; t < 4; ++t) {
    #pragma unroll
    for (int r = 0; r < 4; ++r) {
      b1s[t][r] = b1[16 * t + 4 * q + r] * istep;
      b2s[t][r] = b2[16 * t + 4 * q + r] * istep;
    }
  }
  #pragma unroll
  for (int r = 0; r < 4; ++r) {
    int n = 4 * q + r;
    b3s[r] = (n < 6) ? b3[n] : 0.f;
  }

  // ---- scalarized work decomposition over 4-tile supertiles ----
  const int ntiles = B >> 4;                                   // 65536
  const int nSup   = ntiles >> 2;                              // 16384 supertiles (64 rows each)
  const int nw     = (int)(gridDim.x << 2);                    // 4096 waves
  const int wid    = __builtin_amdgcn_readfirstlane((int)(blockIdx.x << 2) + w);
  const int nIter  = (nSup + nw - 1) / nw;                     // 4
  const int lastS  = nSup - 1;

  float* xb = smem + w * 2176;                                 // two 1088-dword buffers

  const int lane4 = lane * 4;                                  // dword offsets for staging
  const int fbase = bi * 17 + 8 * q;                           // frag base (q<2)
  const int fb2   = bi * 17 + 16;                              // q==2 single element

  // stage one supertile (1088 dw = 4352B contiguous):
  // 4x dwordx4 (dw 0..1023) + 1x dword (dw 1024..1087: one dword/lane, EXACT, no overflow)
  auto stage = [&](int s, float* buf) {
    const float* tp = x + (size_t)s * 1088;
    gld16(tp + lane4,        buf);                             // dw    0..255
    gld16(tp + 256 + lane4,  buf + 256);                       // dw  256..511
    gld16(tp + 512 + lane4,  buf + 512);                       // dw  512..767
    gld16(tp + 768 + lane4,  buf + 768);                       // dw  768..1023
    gld4 (tp + 1024 + lane,  buf + 1024);                      // dw 1024..1087
  };

  const floatx4 zero4 = {0.f, 0.f, 0.f, 0.f};

  // ---- prologue: fill buffer 0 ----
  stage(imin(wid, lastS), xb);

  #pragma unroll 1
  for (int it = 0; it < nIter; ++it) {
    const int gs = imin(wid + it * nw, lastS);
    float* cur = xb + (it & 1) * 1088;

    // retire this buffer's 5 loads; allow last iter's 2 stores to stay outstanding
    if (it == 0) { asm volatile("s_waitcnt vmcnt(0)" ::: "memory"); }
    else         { asm volatile("s_waitcnt vmcnt(2)" ::: "memory"); }

    // issue next supertile into the other buffer (its old contents are fully consumed)
    if (it + 1 < nIter) stage(imin(wid + (it + 1) * nw, lastS), xb + ((it + 1) & 1) * 1088);

    #pragma unroll 1
    for (int k = 0; k < 4; ++k) {
      float* tb = cur + k * 272;

      // fragment gather from LDS (stride-17-dword: max 2-way bank alias = free)
      float xr[8];
      if (q < 2) {
        #pragma unroll
        for (int j = 0; j < 8; ++j) xr[j] = tb[fbase + j];
      } else if (q == 2) {
        xr[0] = tb[fb2];
        #pragma unroll
        for (int j = 1; j < 8; ++j) xr[j] = 0.f;
      } else {
        #pragma unroll
        for (int j = 0; j < 8; ++j) xr[j] = 0.f;
      }

      // input quant -> B-frag: lane holds Xq[row=bi][k=8q+j]
      uint4v ap;
      #pragma unroll
      for (int jp = 0; jp < 4; ++jp)
        ap[jp] = pack2(qclamp(xr[2 * jp] * istep), qclamp(xr[2 * jp + 1] * istep));
      short8 af = __builtin_bit_cast(short8, ap);

      // L1
      floatx4 c1[4];
      #pragma unroll
      for (int t = 0; t < 4; ++t)
        c1[t] = __builtin_amdgcn_mfma_f32_16x16x32_bf16(w1f[t], af, zero4, 0, 0, 0);

      uint4v h1u[2];
      #pragma unroll
      for (int t = 0; t < 4; ++t) {
        float z0 = qclamp(fmaf(c1[t][0], g1, b1s[t][0]));
        float z1 = qclamp(fmaf(c1[t][1], g1, b1s[t][1]));
        float z2 = qclamp(fmaf(c1[t][2], g1, b1s[t][2]));
        float z3 = qclamp(fmaf(c1[t][3], g1, b1s[t][3]));
        h1u[t >> 1][(t & 1) * 2 + 0] = pack2(z0, z1);
        h1u[t >> 1][(t & 1) * 2 + 1] = pack2(z2, z3);
      }
      short8 h1a = __builtin_bit_cast(short8, h1u[0]);
      short8 h1b = __builtin_bit_cast(short8, h1u[1]);

      // L2 (K=64)
      floatx4 c2[4];
      #pragma unroll
      for (int t = 0; t < 4; ++t) {
        c2[t] = __builtin_amdgcn_mfma_f32_16x16x32_bf16(w2f[t][0], h1a, zero4, 0, 0, 0);
        c2[t] = __builtin_amdgcn_mfma_f32_16x16x32_bf16(w2f[t][1], h1b, c2[t], 0, 0, 0);
      }

      uint4v h2u[2];
      #pragma unroll
      for (int t = 0; t < 4; ++t) {
        float z0 = qclamp(fmaf(c2[t][0], g2, b2s[t][0]));
        float z1 = qclamp(fmaf(c2[t][1], g2, b2s[t][1]));
        float z2 = qclamp(fmaf(c2[t][2], g2, b2s[t][2]));
        float z3 = qclamp(fmaf(c2[t][3], g2, b2s[t][3]));
        h2u[t >> 1][(t & 1) * 2 + 0] = pack2(z0, z1);
        h2u[t >> 1][(t & 1) * 2 + 1] = pack2(z2, z3);
      }
      short8 h2a = __builtin_bit_cast(short8, h2u[0]);
      short8 h2b = __builtin_bit_cast(short8, h2u[1]);

      // L3
      floatx4 c3;
      c3 = __builtin_amdgcn_mfma_f32_16x16x32_bf16(w3f[0], h2a, zero4, 0, 0, 0);
      c3 = __builtin_amdgcn_mfma_f32_16x16x32_bf16(w3f[1], h2b, c3, 0, 0, 0);

      float o0 = fmaf(c3[0], sc3, b3s[0]);
      float o1 = fmaf(c3[1], sc3, b3s[1]);
      float o2 = fmaf(c3[2], sc3, b3s[2]);
      float o3 = fmaf(c3[3], sc3, b3s[3]);

      // stage tile-k output IN-PLACE at cur[k*96]: audited -- every write lands on input
      // already consumed in program order (k's own tile gathered above; k<k' regions
      // consumed at earlier k). ds_write_b64, 24B stride.
      float* ob = cur + k * 96;
      if (q == 0) {
        *(float2*)(ob + bi * 6)     = make_float2(o0, o1);
        *(float2*)(ob + bi * 6 + 2) = make_float2(o2, o3);
      } else if (q == 1) {
        *(float2*)(ob + bi * 6 + 4) = make_float2(o0, o1);
      }
    }

    asm volatile("" ::: "memory");                             // pin LDS write->read order
    // batched store of 64 rows x 6 = 384 dw = 1536B contiguous: 2 dwordx4 stores
    {
      float4 v0 = *(const float4*)(cur + lane4);               // dw 0..255
      *(float4*)(out + (size_t)gs * 384 + lane4) = v0;
      if (lane < 32) {
        float4 v1 = *(const float4*)(cur + 256 + lane4);       // dw 256..383
        *(float4*)(out + (size_t)gs * 384 + 256 + lane4) = v1;
      }
    }
  }
}

extern "C" void kernel_launch(void* const* d_in, const int* in_sizes, int n_in,
                              void* d_out, int out_size, void* d_ws, size_t ws_size,
                              hipStream_t stream) {
  const float* x  = (const float*)d_in[0];
  const float* W1 = (const float*)d_in[1];
  const float* b1 = (const float*)d_in[2];
  const float* W2 = (const float*)d_in[3];
  const float* b2 = (const float*)d_in[4];
  const float* W3 = (const float*)d_in[5];
  const float* b3 = (const float*)d_in[6];
  float* out = (float*)d_out;
  const int B = in_sizes[0] / 17;          // 1048576

  dim3 grid(1024), block(256);             // 4096 waves x 4 super-iterations, 4 blocks/CU
  qmlp_fused<<<grid, block, 0, stream>>>(x, W1, b1, W2, b2, W3, b3, out, B);
}